// Round 1
// baseline (249.154 us; speedup 1.0000x reference)
//
#include <hip/hip_runtime.h>

// Depthwise 3x3 conv (stride 1, pad 1), 2 filters per input channel,
// output channels interleaved [2c, 2c+1], + bias.
// Shapes: x (32,192,56,56) f32; w1,w2 (C,9); bias (2C); out (32,384,56,56).

#define BB 32
#define CC 192
#define HH 56
#define WW 56
#define W4 (WW / 4)  // 14 float4 segments per row

__global__ __launch_bounds__(256) void dwconv2_kernel(
    const float* __restrict__ x,
    const float* __restrict__ w1,
    const float* __restrict__ w2,
    const float* __restrict__ bias,
    float* __restrict__ out)
{
    const int total = BB * CC * HH * W4;
    int idx = blockIdx.x * blockDim.x + threadIdx.x;
    if (idx >= total) return;

    int w4 = idx % W4;
    int t  = idx / W4;
    int h  = t % HH;
    t /= HH;
    int c  = t % CC;
    int b  = t / CC;

    // Per-channel weights (broadcast within wave; L1 hits)
    float a1[9], a2[9];
#pragma unroll
    for (int i = 0; i < 9; ++i) {
        a1[i] = w1[c * 9 + i];
        a2[i] = w2[c * 9 + i];
    }
    const float bias1 = bias[2 * c];
    const float bias2 = bias[2 * c + 1];

    const float* xp = x + ((size_t)(b * CC + c) * HH) * WW;
    const int w0 = w4 * 4;

    // Gather 3 rows x 6 columns (w0-1 .. w0+4), zero-padded at edges.
    float row[3][6];
#pragma unroll
    for (int r = 0; r < 3; ++r) {
        int hh = h - 1 + r;
        bool hv = (hh >= 0) && (hh < HH);
        const float* rp = xp + hh * WW + w0;
        float4 mid = hv ? *(const float4*)rp : make_float4(0.f, 0.f, 0.f, 0.f);
        float left  = (hv && w0 > 0)        ? rp[-1] : 0.f;
        float right = (hv && (w0 + 4) < WW) ? rp[4]  : 0.f;
        row[r][0] = left;
        row[r][1] = mid.x;
        row[r][2] = mid.y;
        row[r][3] = mid.z;
        row[r][4] = mid.w;
        row[r][5] = right;
    }

    float o1[4], o2[4];
#pragma unroll
    for (int p = 0; p < 4; ++p) {
        float s1 = bias1, s2 = bias2;
#pragma unroll
        for (int r = 0; r < 3; ++r) {
#pragma unroll
            for (int kc = 0; kc < 3; ++kc) {
                float v = row[r][p + kc];
                s1 += v * a1[r * 3 + kc];
                s2 += v * a2[r * 3 + kc];
            }
        }
        o1[p] = s1;
        o2[p] = s2;
    }

    float* op = out + (((size_t)(b * 2 * CC + 2 * c) * HH + h) * WW + w0);
    *(float4*)op = make_float4(o1[0], o1[1], o1[2], o1[3]);
    *(float4*)(op + (size_t)HH * WW) = make_float4(o2[0], o2[1], o2[2], o2[3]);
}

extern "C" void kernel_launch(void* const* d_in, const int* in_sizes, int n_in,
                              void* d_out, int out_size, void* d_ws, size_t ws_size,
                              hipStream_t stream) {
    const float* x  = (const float*)d_in[0];
    const float* w1 = (const float*)d_in[1];
    const float* w2 = (const float*)d_in[2];
    const float* bs = (const float*)d_in[3];
    float* out = (float*)d_out;

    const int total = BB * CC * HH * W4;  // 4,816,896 threads
    const int block = 256;
    const int grid = (total + block - 1) / block;
    dwconv2_kernel<<<grid, block, 0, stream>>>(x, w1, w2, bs, out);
}

// Round 3
// 239.106 us; speedup vs baseline: 1.0420x; 1.0420x over previous
//
#include <hip/hip_runtime.h>

// Depthwise 3x3 conv (stride 1, pad 1), 2 filters per input channel,
// output channels interleaved [2c, 2c+1], + bias.
// x (32,192,56,56) f32; w1,w2 (C,9); bias (2C); out (32,384,56,56).
//
// One block per (b,c) plane. 784 threads = 56 rows x 14 float4-segments.
// Plane staged to LDS (58x60, zero border) with 1 coalesced float4/thread;
// weights staged to LDS by <=20 threads (kills per-lane VMEM weight loads);
// stencil entirely from LDS; 2 nontemporal float4 stores per thread.

#define BB 32
#define CC 192
#define HH 56
#define WW 56
#define W4 14
#define PITCH 60   // floats per LDS row; 60 mod 32 = 28 spreads banks per row
#define LROWS 58

typedef float f32x4 __attribute__((ext_vector_type(4)));

__global__ __launch_bounds__(784) void dwconv2_lds_kernel(
    const float* __restrict__ x,
    const float* __restrict__ w1,
    const float* __restrict__ w2,
    const float* __restrict__ bias,
    float* __restrict__ out)
{
    __shared__ float tile[LROWS * PITCH];
    __shared__ float wts[20];   // a1[9], a2[9], bias1, bias2

    const int bc = blockIdx.x;         // b*CC + c
    const int c  = bc % CC;

    const int t  = threadIdx.x;        // 0..783
    const int h  = t / W4;             // image row 0..55
    const int w4 = t % W4;
    const int w0 = w4 * 4;             // image col of first output pixel

    // --- stage weights to LDS (broadcast source; <=20 VMEM insts per block)
    if (t < 9)        wts[t]      = w1[c * 9 + t];
    else if (t < 18)  wts[t]      = w2[c * 9 + (t - 9)];
    else if (t < 20)  wts[t]      = bias[2 * c + (t - 18)];

    // --- zero the halo border (rows 0,57; cols 0,57)
    if (t < 60)            tile[t] = 0.f;                         // row 0
    else if (t < 120)      tile[57 * PITCH + (t - 60)] = 0.f;     // row 57
    else if (t < 176)      tile[(t - 119) * PITCH] = 0.f;         // col 0, rows 1..56
    else if (t < 232)      tile[(t - 175) * PITCH + 57] = 0.f;    // col 57, rows 1..56

    // --- stage plane: one coalesced float4 per thread (x read exactly once)
    const f32x4 v = __builtin_nontemporal_load(
        (const f32x4*)(x + ((size_t)bc * HH + h) * WW + w0));
    float* dst = &tile[(h + 1) * PITCH + 1 + w0];   // image (h, w0) -> LDS (h+1, w0+1)
    dst[0] = v.x; dst[1] = v.y; dst[2] = v.z; dst[3] = v.w;

    __syncthreads();

    // --- weights to registers (broadcast LDS reads, lgkm pipe)
    float a1[9], a2[9];
#pragma unroll
    for (int i = 0; i < 9; ++i) { a1[i] = wts[i]; a2[i] = wts[9 + i]; }
    const float bias1 = wts[18], bias2 = wts[19];

    float o1[4], o2[4];
#pragma unroll
    for (int p = 0; p < 4; ++p) { o1[p] = bias1; o2[p] = bias2; }

    // --- stencil from LDS: rows h..h+2, cols w0..w0+5 (image cols w0-1..w0+4)
#pragma unroll
    for (int r = 0; r < 3; ++r) {
        const float* rp = &tile[(h + r) * PITCH + w0];
        float rv[6];
#pragma unroll
        for (int j = 0; j < 6; ++j) rv[j] = rp[j];
#pragma unroll
        for (int p = 0; p < 4; ++p) {
#pragma unroll
            for (int kc = 0; kc < 3; ++kc) {
                o1[p] += rv[p + kc] * a1[r * 3 + kc];
                o2[p] += rv[p + kc] * a2[r * 3 + kc];
            }
        }
    }

    // --- nontemporal stores (out never re-read; don't thrash L2/L3)
    const size_t obase = (((size_t)(bc * 2) * HH) + h) * WW + w0;  // channel 2c
    f32x4 s1; s1.x = o1[0]; s1.y = o1[1]; s1.z = o1[2]; s1.w = o1[3];
    f32x4 s2; s2.x = o2[0]; s2.y = o2[1]; s2.z = o2[2]; s2.w = o2[3];
    __builtin_nontemporal_store(s1, (f32x4*)(out + obase));
    __builtin_nontemporal_store(s2, (f32x4*)(out + obase + (size_t)HH * WW));
}

extern "C" void kernel_launch(void* const* d_in, const int* in_sizes, int n_in,
                              void* d_out, int out_size, void* d_ws, size_t ws_size,
                              hipStream_t stream) {
    const float* x  = (const float*)d_in[0];
    const float* w1 = (const float*)d_in[1];
    const float* w2 = (const float*)d_in[2];
    const float* bs = (const float*)d_in[3];
    float* out = (float*)d_out;

    dwconv2_lds_kernel<<<BB * CC, 784, 0, stream>>>(x, w1, w2, bs, out);
}